// Round 16
// baseline (370.143 us; speedup 1.0000x reference)
//
#include <hip/hip_runtime.h>
#include <hip/hip_bf16.h>
#include <hip/hip_fp16.h>

#define TABN   4096
#define ROWS   (TABN + 1)           // table rows per interaction
#define DMAX   6.5f
#define DELTA  (DMAX / (float)TABN)
#define INVD   ((float)TABN / DMAX)
#define LOG2F_ 0.6931471805599453f
#define SBITS  8                    // 256 tgt-nodes per bucket (R15: place occupancy)
#define TILE   2048                 // edges per stage tile

typedef _Float16 f16x8 __attribute__((ext_vector_type(8)));
typedef float    f32x4 __attribute__((ext_vector_type(4)));

__device__ __forceinline__ float ssp(float x) {
    return fmaxf(x, 0.f) + __logf(1.f + __expf(-fabsf(x))) - LOG2F_;
}

// ---------------- filter lookup table: W_i(d) for d = t*DELTA ----------------
__global__ void ftab_kernel(const float* __restrict__ fw1, const float* __restrict__ fb1,
                            const float* __restrict__ fw2, const float* __restrict__ fb2,
                            float* __restrict__ ftab) {
    int t = blockIdx.x;          // 0..ROWS-1
    int i = blockIdx.y;          // interaction 0/1
    int j = threadIdx.x;         // 0..63 channel
    float d = (float)t * DELTA;
    float acc = fb1[i * 64 + j];
    for (int k = 0; k < 51; ++k) {
        float u = d - 0.1f * (float)k;
        float r = __expf(-10.f * u * u);
        acc = fmaf(r, fw1[((size_t)i * 51 + k) * 64 + j], acc);
    }
    __shared__ float h[64];
    h[j] = ssp(acc);
    __syncthreads();
    float o = fb2[i * 64 + j];
    for (int k = 0; k < 64; ++k)
        o = fmaf(h[k], fw2[((size_t)i * 64 + k) * 64 + j], o);
    ftab[((size_t)i * ROWS + t) * 64 + j] = o;
}

// ------- pack lerp endpoints as fp16 pair: 4B/entry, 1MB/interaction --------
__global__ void fpack_kernel(const float* __restrict__ ftab, __half2* __restrict__ fpair) {
    int t = blockIdx.x, i = blockIdx.y, j = threadIdx.x;
    const float* r = ftab + ((size_t)i * ROWS + t) * 64;
    fpair[((size_t)i * TABN + t) * 64 + j] = __floats2half2_rn(r[j], r[j + 64]);
}

// ------- pack/transpose the 7 64x64 node-MLP weights to [n][k] fp16 ---------
__global__ void wpack_kernel(const float* w0, const float* w1, const float* w2,
                             const float* w3, const float* w4, const float* w5,
                             const float* w6, __half* __restrict__ wt) {
    const float* ws[7] = {w0, w1, w2, w3, w4, w5, w6};
    int nrow = blockIdx.x, mat = blockIdx.y, k = threadIdx.x;
    wt[((size_t)mat * 64 + nrow) * 64 + k] = __float2half(ws[mat][k * 64 + nrow]);
}

// ---------------- bucket histogram (LDS-privatized, 512 slots) ----------------
__global__ void bhist_kernel(const int* __restrict__ ei, int* __restrict__ bcnt, int E) {
    __shared__ int h[512];
    int tid = threadIdx.x;
    h[tid] = 0; h[tid + 256] = 0;
    __syncthreads();
    for (int e = blockIdx.x * blockDim.x + tid; e < E; e += gridDim.x * blockDim.x)
        atomicAdd(&h[ei[E + e] >> SBITS], 1);
    __syncthreads();
    if (h[tid]) atomicAdd(&bcnt[tid], h[tid]);
    if (h[tid + 256]) atomicAdd(&bcnt[tid + 256], h[tid + 256]);
}

// ---------------- bucket exclusive scan (parallel, one 512-thread block) -----
__global__ void bscan_kernel(const int* __restrict__ bcnt, int* __restrict__ bbase,
                             int* __restrict__ bcur, int nbuck) {
    __shared__ int sm[512];
    int tid = threadIdx.x;     // 512 threads
    int v = (tid < nbuck) ? bcnt[tid] : 0;
    sm[tid] = v;
    __syncthreads();
    for (int o = 1; o < 512; o <<= 1) {
        int t = (tid >= o) ? sm[tid - o] : 0;
        __syncthreads();
        sm[tid] += t;
        __syncthreads();
    }
    if (tid < nbuck) { bbase[tid] = sm[tid] - v; bcur[tid] = sm[tid] - v; }
    if (tid == 511) bbase[nbuck] = sm[511];
}

// ------- stage: LDS multisplit of edge tiles into bucket-ordered stg ---------
// payload: w0 = src | (t&255)<<17 ; w1 = ti<<20 | frac_q20
__global__ __launch_bounds__(256, 4)
void stage_kernel(const float* __restrict__ pos, const int* __restrict__ ei,
                  int* __restrict__ bcur, int2* __restrict__ stg, int E, int nbuck) {
    __shared__ int hist[512], loff[512], gbase[512], ps[256];
    __shared__ int2 sp[TILE];
    __shared__ short sb[TILE];
    int tid = threadIdx.x;
    int tile0 = blockIdx.x * TILE;
    int cnt = min(TILE, E - tile0);
    hist[tid] = 0; hist[tid + 256] = 0;
    __syncthreads();
    int myrank[8], myb[8]; int2 mypay[8];
#pragma unroll
    for (int u = 0; u < 8; ++u) {
        int i = u * 256 + tid;
        myb[u] = -1;
        if (i < cnt) {
            int e = tile0 + i;
            int s = ei[e], t = ei[E + e];
            float dx = pos[3 * s]     - pos[3 * t];
            float dy = pos[3 * s + 1] - pos[3 * t + 1];
            float dz = pos[3 * s + 2] - pos[3 * t + 2];
            float d = sqrtf(dx * dx + dy * dy + dz * dz);
            float ds = fminf(d, DMAX) * INVD;
            int ti = min((int)ds, TABN - 1);
            int frq = min((int)((ds - (float)ti) * 1048576.f), 1048575);
            mypay[u] = make_int2(s | ((t & 255) << 17), (ti << 20) | frq);
            myb[u] = t >> SBITS;
            myrank[u] = atomicAdd(&hist[myb[u]], 1);
        }
    }
    __syncthreads();
    // pair-scan over 512 histogram entries with 256 threads
    int h0 = hist[2 * tid], h1 = hist[2 * tid + 1];
    int pr = h0 + h1;
    ps[tid] = pr;
    __syncthreads();
    for (int o = 1; o < 256; o <<= 1) {
        int v = (tid >= o) ? ps[tid - o] : 0;
        __syncthreads();
        ps[tid] += v;
        __syncthreads();
    }
    int ex = ps[tid] - pr;
    loff[2 * tid] = ex;
    loff[2 * tid + 1] = ex + h0;
    if (2 * tid < nbuck && h0 > 0) gbase[2 * tid] = atomicAdd(&bcur[2 * tid], h0);
    if (2 * tid + 1 < nbuck && h1 > 0) gbase[2 * tid + 1] = atomicAdd(&bcur[2 * tid + 1], h1);
    __syncthreads();
#pragma unroll
    for (int u = 0; u < 8; ++u)
        if (myb[u] >= 0) {
            int idx = loff[myb[u]] + myrank[u];
            sp[idx] = mypay[u];
            sb[idx] = (short)myb[u];
        }
    __syncthreads();
    for (int i = tid; i < cnt; i += 256) {
        int b = sb[i];
        int2 v = sp[i];
        long long raw = (unsigned)v.x | ((long long)v.y << 32);
        __builtin_nontemporal_store(raw, (long long*)(stg + gbase[b] + (i - loff[b])));
    }
}

// ------- place: per 256-node bucket, exact CSR with LDS-only atomics ---------
__global__ __launch_bounds__(256)
void place_kernel(const int2* __restrict__ stg, const int* __restrict__ bbase,
                  int* __restrict__ off, int2* __restrict__ edata, int n, int nbuck) {
    int b = blockIdx.x;
    int n0 = b << SBITS;
    int nn = min(256, n - n0);
    int q0 = bbase[b], q1 = bbase[b + 1];
    __shared__ int cnt[256], cur[256], sc[256];
    int tid = threadIdx.x;
    cnt[tid] = 0;
    __syncthreads();
    for (int q = q0 + tid; q < q1; q += 256)
        atomicAdd(&cnt[(stg[q].x >> 17) & 255], 1);
    __syncthreads();
    int c = cnt[tid];
    sc[tid] = c;
    __syncthreads();
    for (int o = 1; o < 256; o <<= 1) {
        int v = (tid >= o) ? sc[tid - o] : 0;
        __syncthreads();
        sc[tid] += v;
        __syncthreads();
    }
    int run = sc[tid] - c;
    cur[tid] = run;
    if (tid < nn) off[n0 + tid] = q0 + run;
    if (b == nbuck - 1 && tid == 0) off[n] = q1;
    __syncthreads();
    for (int q = q0 + tid; q < q1; q += 256) {
        long long raw = __builtin_nontemporal_load((const long long*)(stg + q));
        int lo = (int)(unsigned)raw;
        int p = atomicAdd(&cur[(lo >> 17) & 255], 1);
        __builtin_nontemporal_store(raw, (long long*)(edata + q0 + p));
    }
}

// ---------------- solvent head for the 4 unique solvent rows ----------------
__global__ void solv_kernel(const float* __restrict__ emb_solv,
                            const float* __restrict__ w1, const float* __restrict__ b1,
                            const float* __restrict__ w2, const float* __restrict__ b2,
                            float* __restrict__ s4) {
    __shared__ float h[4][64];
    int t = threadIdx.x, r = t >> 6, j = t & 63;
    float acc = b1[j];
    for (int k = 0; k < 64; ++k) acc = fmaf(emb_solv[r * 64 + k], w1[k * 64 + j], acc);
    h[r][j] = ssp(acc);
    __syncthreads();
    if (j < 32) {
        float a = b2[j];
        for (int k = 0; k < 64; ++k) a = fmaf(h[r][k], w2[k * 32 + j], a);
        s4[r * 32 + j] = a;
    }
}

// ------------- m0 = emb_z[z]@W+b, fp16 out; reads L1-resident emb table -----
__global__ __launch_bounds__(256, 4)
void mm1h_kernel(const int* __restrict__ z, const float* __restrict__ emb,
                 const float* __restrict__ w, const float* __restrict__ b,
                 __half* __restrict__ out, int n) {
    int tid = threadIdx.x;
    int q = __builtin_amdgcn_readfirstlane(tid >> 6);   // 0..3, wave-uniform
    int node = blockIdx.x * 64 + (tid & 63);
    node = min(node, n - 1);
    int zi = z[node];
    const float4* in4 = (const float4*)(emb + (size_t)zi * 64);  // 25KB table: L1 hit
    const float* wq = w + q * 16;
    const float* bq = b + q * 16;
    float acc[16];
#pragma unroll
    for (int j = 0; j < 16; ++j) acc[j] = bq[j];
#pragma unroll 2
    for (int kk = 0; kk < 16; ++kk) {
        float4 xv = in4[kk];
        const float* w0 = wq + kk * 256;
#pragma unroll
        for (int j = 0; j < 16; ++j) acc[j] = fmaf(xv.x, w0[j],       acc[j]);
#pragma unroll
        for (int j = 0; j < 16; ++j) acc[j] = fmaf(xv.y, w0[64 + j],  acc[j]);
#pragma unroll
        for (int j = 0; j < 16; ++j) acc[j] = fmaf(xv.z, w0[128 + j], acc[j]);
#pragma unroll
        for (int j = 0; j < 16; ++j) acc[j] = fmaf(xv.w, w0[192 + j], acc[j]);
    }
    __half2* o2 = (__half2*)(out + (size_t)node * 64 + q * 16);
#pragma unroll
    for (int c = 0; c < 8; ++c)
        o2[c] = __floats2half2_rn(acc[2 * c], acc[2 * c + 1]);
}

// ---------------- per-node aggregation: agg[t] = sum_e m[src]*W(d) ----------
// wave per tgt node; edata nontemporal (streamed) + SALU decode; m fp16 rows
// (cached — keep in L2), fpair L2-resident; agg output nontemporal (streamed).
__global__ void agg_kernel(const int* __restrict__ off, const int2* __restrict__ edata,
                           const __half* __restrict__ m, const __half2* __restrict__ fpair,
                           __half* __restrict__ agg, int n) {
    int wave = (blockIdx.x * blockDim.x + threadIdx.x) >> 6;
    int lane = threadIdx.x & 63;
    if (wave >= n) return;
    int e0 = __builtin_amdgcn_readfirstlane(off[wave]);
    int e1 = __builtin_amdgcn_readfirstlane(off[wave + 1]);
    const float FRS = 1.f / 1048576.f;
    float acc[4] = {0.f, 0.f, 0.f, 0.f};
    int e = e0;
    for (; e + 8 <= e1; e += 8) {
        float mv[8], wv[8];
#pragma unroll
        for (int u = 0; u < 8; ++u) {
            long long raw = __builtin_nontemporal_load((const long long*)(edata + e + u));
            int px = __builtin_amdgcn_readfirstlane((int)(unsigned)raw);
            int py = __builtin_amdgcn_readfirstlane((int)(raw >> 32));
            int s = px & 0x1FFFF;
            unsigned ti = ((unsigned)py) >> 20;
            float fr = (float)(py & 0xFFFFF) * FRS;
            mv[u] = __half2float(m[(size_t)s * 64 + lane]);
            float2 wf = __half22float2(fpair[(size_t)ti * 64 + lane]);
            wv[u] = fmaf(fr, wf.y - wf.x, wf.x);
        }
#pragma unroll
        for (int u = 0; u < 8; ++u) acc[u & 3] = fmaf(mv[u], wv[u], acc[u & 3]);
    }
    for (; e + 4 <= e1; e += 4) {
        float mv[4], wv[4];
#pragma unroll
        for (int u = 0; u < 4; ++u) {
            long long raw = __builtin_nontemporal_load((const long long*)(edata + e + u));
            int px = __builtin_amdgcn_readfirstlane((int)(unsigned)raw);
            int py = __builtin_amdgcn_readfirstlane((int)(raw >> 32));
            int s = px & 0x1FFFF;
            unsigned ti = ((unsigned)py) >> 20;
            float fr = (float)(py & 0xFFFFF) * FRS;
            mv[u] = __half2float(m[(size_t)s * 64 + lane]);
            float2 wf = __half22float2(fpair[(size_t)ti * 64 + lane]);
            wv[u] = fmaf(fr, wf.y - wf.x, wf.x);
        }
#pragma unroll
        for (int u = 0; u < 4; ++u) acc[u] = fmaf(mv[u], wv[u], acc[u]);
    }
    for (; e < e1; ++e) {
        long long raw = __builtin_nontemporal_load((const long long*)(edata + e));
        int px = __builtin_amdgcn_readfirstlane((int)(unsigned)raw);
        int py = __builtin_amdgcn_readfirstlane((int)(raw >> 32));
        int s = px & 0x1FFFF;
        unsigned ti = ((unsigned)py) >> 20;
        float fr = (float)(py & 0xFFFFF) * FRS;
        float mm = __half2float(m[(size_t)s * 64 + lane]);
        float2 wf = __half22float2(fpair[(size_t)ti * 64 + lane]);
        acc[0] = fmaf(mm, fmaf(fr, wf.y - wf.x, wf.x), acc[0]);
    }
    float sum = (acc[0] + acc[1]) + (acc[2] + acc[3]);
    unsigned short hv = __half_as_ushort(__float2half(sum));
    __builtin_nontemporal_store(hv, (unsigned short*)(agg + (size_t)wave * 64 + lane));
}

// ===== MFMA 2-layer node MLP: out = ssp(in@W1+b1)@W2+b2 (+res) (+next m) =====
// RESMODE: 0 = none, 1 = fp16 buffer, 2 = emb_z[z[r]] (L1-resident, kills the
// embed kernel). Layouts as R15 (HW-verified).
template <int RESMODE, bool EMIT_M>
__global__ __launch_bounds__(256, 4)
void mfmlp_kernel(const __half* __restrict__ in,
                  const __half* __restrict__ w1t, const float* __restrict__ b1,
                  const __half* __restrict__ w2t, const float* __restrict__ b2,
                  const __half* __restrict__ res, const int* __restrict__ z,
                  const float* __restrict__ embf, __half* __restrict__ out,
                  const __half* __restrict__ lwt, const float* __restrict__ lb,
                  __half* __restrict__ mout, int n) {
    __shared__ __half hls[4][16][72];
    int tid = threadIdx.x;
    int w = tid >> 6, l = tid & 63;
    int lm = l & 15, lg = l >> 4;
    int base = blockIdx.x * 64 + w * 16;
    int arow = min(base + lm, n - 1);

    // ---- layer 1 ----
    f32x4 acc[4];
#pragma unroll
    for (int nt = 0; nt < 4; ++nt) acc[nt] = (f32x4){0.f, 0.f, 0.f, 0.f};
#pragma unroll
    for (int s = 0; s < 2; ++s) {
        f16x8 a = *(const f16x8*)(in + (size_t)arow * 64 + 32 * s + 8 * lg);
#pragma unroll
        for (int nt = 0; nt < 4; ++nt) {
            f16x8 b = *(const f16x8*)(w1t + (size_t)(lm + 16 * nt) * 64 + 32 * s + 8 * lg);
            acc[nt] = __builtin_amdgcn_mfma_f32_16x16x32_f16(a, b, acc[nt], 0, 0, 0);
        }
    }
#pragma unroll
    for (int nt = 0; nt < 4; ++nt) {
        float bb = b1[lm + 16 * nt];
#pragma unroll
        for (int i = 0; i < 4; ++i)
            hls[w][lg * 4 + i][lm + 16 * nt] = __float2half(ssp(acc[nt][i] + bb));
    }

    // ---- layer 2 ----
    f32x4 acc2[4];
#pragma unroll
    for (int nt = 0; nt < 4; ++nt) acc2[nt] = (f32x4){0.f, 0.f, 0.f, 0.f};
#pragma unroll
    for (int s = 0; s < 2; ++s) {
        f16x8 a = *(const f16x8*)(&hls[w][lm][32 * s + 8 * lg]);
#pragma unroll
        for (int nt = 0; nt < 4; ++nt) {
            f16x8 b = *(const f16x8*)(w2t + (size_t)(lm + 16 * nt) * 64 + 32 * s + 8 * lg);
            acc2[nt] = __builtin_amdgcn_mfma_f32_16x16x32_f16(a, b, acc2[nt], 0, 0, 0);
        }
    }
#pragma unroll
    for (int nt = 0; nt < 4; ++nt) {
        float bb = b2[lm + 16 * nt];
#pragma unroll
        for (int i = 0; i < 4; ++i) {
            int r = base + lg * 4 + i;
            if (r < n) {
                float v = acc2[nt][i] + bb;
                if constexpr (RESMODE == 1)
                    v += __half2float(res[(size_t)r * 64 + lm + 16 * nt]);
                else if constexpr (RESMODE == 2)
                    v += embf[(size_t)z[r] * 64 + lm + 16 * nt];
                out[(size_t)r * 64 + lm + 16 * nt] = __float2half(v);
                if constexpr (EMIT_M) hls[w][lg * 4 + i][lm + 16 * nt] = __float2half(v);
            }
        }
    }
    if constexpr (EMIT_M) {
        // ---- layer 3: next m = out-tile @ LW ----
        f32x4 acc3[4];
#pragma unroll
        for (int nt = 0; nt < 4; ++nt) acc3[nt] = (f32x4){0.f, 0.f, 0.f, 0.f};
#pragma unroll
        for (int s = 0; s < 2; ++s) {
            f16x8 a = *(const f16x8*)(&hls[w][lm][32 * s + 8 * lg]);
#pragma unroll
            for (int nt = 0; nt < 4; ++nt) {
                f16x8 b = *(const f16x8*)(lwt + (size_t)(lm + 16 * nt) * 64 + 32 * s + 8 * lg);
                acc3[nt] = __builtin_amdgcn_mfma_f32_16x16x32_f16(a, b, acc3[nt], 0, 0, 0);
            }
        }
#pragma unroll
        for (int nt = 0; nt < 4; ++nt) {
            float bb = lb[lm + 16 * nt];
#pragma unroll
            for (int i = 0; i < 4; ++i) {
                int r = base + lg * 4 + i;
                if (r < n)
                    mout[(size_t)r * 64 + lm + 16 * nt] = __float2half(acc3[nt][i] + bb);
            }
        }
    }
}

// ---------------- scatter-mean pooling (fp16 input, batch sorted) -----------
__global__ void pool_kernel(const __half* __restrict__ h, const int* __restrict__ batch,
                            float* __restrict__ pooled, int n_nodes) {
    int g = blockIdx.x, j = threadIdx.x;   // block = 64
    int lo = 0, hi = n_nodes;
    while (lo < hi) { int mid = (lo + hi) >> 1; if (batch[mid] < g) lo = mid + 1; else hi = mid; }
    int start = lo;
    int lo2 = start, hi2 = n_nodes;
    while (lo2 < hi2) { int mid = (lo2 + hi2) >> 1; if (batch[mid] < g + 1) lo2 = mid + 1; else hi2 = mid; }
    int end = lo2;
    float acc = 0.f;
    for (int r = start; r < end; ++r) acc += __half2float(h[(size_t)r * 64 + j]);
    float cnt = (float)(end - start);
    pooled[(size_t)g * 64 + j] = acc / fmaxf(cnt, 1.f);
}

// ---------------- final graph head: 96 -> 128 -> 32 -> 1 --------------------
__global__ void post2_kernel(const float* __restrict__ pooled, const float* __restrict__ s4,
                             const int* __restrict__ solvent,
                             const float* __restrict__ w1, const float* __restrict__ b1,
                             const float* __restrict__ w2, const float* __restrict__ b2,
                             const float* __restrict__ w3, const float* __restrict__ b3,
                             float* __restrict__ out) {
    __shared__ float in96[96];
    __shared__ float l1[128];
    __shared__ float l2[32];
    int g = blockIdx.x, t = threadIdx.x;   // block = 128
    if (t < 64)      in96[t] = pooled[(size_t)g * 64 + t];
    else if (t < 96) in96[t] = s4[solvent[g] * 32 + (t - 64)];
    __syncthreads();
    float acc = b1[t];
    for (int k = 0; k < 96; ++k) acc = fmaf(in96[k], w1[k * 128 + t], acc);
    l1[t] = ssp(acc);
    __syncthreads();
    if (t < 32) {
        float a = b2[t];
        for (int k = 0; k < 128; ++k) a = fmaf(l1[k], w2[k * 32 + t], a);
        l2[t] = ssp(a);
    }
    __syncthreads();
    if (t < 32) {
        float p = l2[t] * w3[t];
        for (int o = 16; o >= 1; o >>= 1) p += __shfl_down(p, o);
        if (t == 0) out[g] = p + b3[0];
    }
}

extern "C" void kernel_launch(void* const* d_in, const int* in_sizes, int n_in,
                              void* d_out, int out_size, void* d_ws, size_t ws_size,
                              hipStream_t stream) {
    const float* pos      = (const float*)d_in[0];
    const int*   ei       = (const int*)d_in[1];
    const int*   z        = (const int*)d_in[2];
    const int*   batch    = (const int*)d_in[3];
    const int*   solvent  = (const int*)d_in[4];
    const float* emb_z    = (const float*)d_in[5];
    const float* emb_solv = (const float*)d_in[6];
    const float* solv_w1  = (const float*)d_in[7];  const float* solv_b1 = (const float*)d_in[8];
    const float* solv_w2  = (const float*)d_in[9];  const float* solv_b2 = (const float*)d_in[10];
    const float* lin1_w   = (const float*)d_in[11]; const float* lin1_b  = (const float*)d_in[12];
    const float* mlp_w1   = (const float*)d_in[13]; const float* mlp_b1  = (const float*)d_in[14];
    const float* mlp_w2   = (const float*)d_in[15]; const float* mlp_b2  = (const float*)d_in[16];
    const float* filt_w1  = (const float*)d_in[17]; const float* filt_b1 = (const float*)d_in[18];
    const float* filt_w2  = (const float*)d_in[19]; const float* filt_b2 = (const float*)d_in[20];
    const float* post_w1  = (const float*)d_in[21]; const float* post_b1 = (const float*)d_in[22];
    const float* post_w2  = (const float*)d_in[23]; const float* post_b2 = (const float*)d_in[24];
    const float* p2w1 = (const float*)d_in[25]; const float* p2b1 = (const float*)d_in[26];
    const float* p2w2 = (const float*)d_in[27]; const float* p2b2 = (const float*)d_in[28];
    const float* p2w3 = (const float*)d_in[29]; const float* p2b3 = (const float*)d_in[30];
    float* out = (float*)d_out;

    const int N = in_sizes[2];
    const int E = in_sizes[1] / 2;
    const int G = in_sizes[4];
    const int NBUCK = (N + (1 << SBITS) - 1) >> SBITS;

    char* wp = (char*)d_ws;
    auto alloc = [&](size_t bytes) -> void* {
        void* r = (void*)wp;
        wp += (bytes + 255) & ~(size_t)255;
        return r;
    };
    int2*    stg    = (int2*)   alloc((size_t)E * 8);
    int2*    edata  = (int2*)   alloc((size_t)E * 8);
    int*     bcnt   = (int*)    alloc(512 * 4);
    int*     bbase  = (int*)    alloc(513 * 4);
    int*     bcur   = (int*)    alloc(512 * 4);
    int*     off    = (int*)    alloc((size_t)(N + 1) * 4);
    float*   ftab   = (float*)  alloc((size_t)2 * ROWS * 64 * 4);
    __half2* fpair  = (__half2*)alloc((size_t)2 * TABN * 64 * 4);
    __half*  wt     = (__half*) alloc((size_t)7 * 4096 * 2);
    float*   s4     = (float*)  alloc(4 * 32 * 4);
    __half*  x_h    = (__half*) alloc((size_t)N * 64 * 2);
    __half*  m_h    = (__half*) alloc((size_t)N * 64 * 2);
    __half*  m_h2   = (__half*) alloc((size_t)N * 64 * 2);
    __half*  agg_h  = (__half*) alloc((size_t)N * 64 * 2);
    __half*  hbuf   = (__half*) alloc((size_t)N * 64 * 2);
    float*   pooled = (float*)  alloc((size_t)G * 64 * 4);
    (void)ws_size; (void)n_in; (void)out_size;

    hipMemsetAsync(bcnt, 0, 512 * 4, stream);

    ftab_kernel<<<dim3(ROWS, 2), 64, 0, stream>>>(filt_w1, filt_b1, filt_w2, filt_b2, ftab);
    fpack_kernel<<<dim3(TABN, 2), 64, 0, stream>>>(ftab, fpair);
    // wt: 0=mlp_w1[0] 1=mlp_w2[0] 2=mlp_w1[1] 3=mlp_w2[1] 4=post_w1 5=post_w2 6=lin1_w[1]
    wpack_kernel<<<dim3(64, 7), 64, 0, stream>>>(mlp_w1, mlp_w2, mlp_w1 + 4096,
                                                 mlp_w2 + 4096, post_w1, post_w2,
                                                 lin1_w + 4096, wt);
    bhist_kernel<<<512, 256, 0, stream>>>(ei, bcnt, E);
    bscan_kernel<<<1, 512, 0, stream>>>(bcnt, bbase, bcur, NBUCK);
    stage_kernel<<<(E + TILE - 1) / TILE, 256, 0, stream>>>(pos, ei, bcur, stg, E, NBUCK);
    place_kernel<<<NBUCK, 256, 0, stream>>>(stg, bbase, off, edata, N, NBUCK);
    solv_kernel<<<1, 256, 0, stream>>>(emb_solv, solv_w1, solv_b1, solv_w2, solv_b2, s4);

    int mmg = (N + 63) / 64;
    // interaction 0: m0 = emb_z[z] @ lin1[0]
    mm1h_kernel<<<mmg, 256, 0, stream>>>(z, emb_z, lin1_w, lin1_b, m_h, N);
    agg_kernel<<<(N + 3) / 4, 256, 0, stream>>>(off, edata, m_h, fpair, agg_h, N);
    // MFMA MLP + residual(from emb) -> x_h, emit m1 = x_h @ lin1[1]
    mfmlp_kernel<2, true><<<mmg, 256, 0, stream>>>(
        agg_h, wt, mlp_b1, wt + 4096, mlp_b2, nullptr, z, emb_z, x_h,
        wt + 6 * 4096, lin1_b + 64, m_h2, N);
    // interaction 1
    agg_kernel<<<(N + 3) / 4, 256, 0, stream>>>(off, edata, m_h2,
                                                fpair + (size_t)TABN * 64, agg_h, N);
    mfmlp_kernel<1, false><<<mmg, 256, 0, stream>>>(
        agg_h, wt + 2 * 4096, mlp_b1 + 64, wt + 3 * 4096, mlp_b2 + 64, x_h,
        nullptr, nullptr, x_h, nullptr, nullptr, nullptr, N);
    // post MLP: hbuf = ssp(x@pw1+b1)@pw2+b2 (fp16, feeds pool only)
    mfmlp_kernel<0, false><<<mmg, 256, 0, stream>>>(
        x_h, wt + 4 * 4096, post_b1, wt + 5 * 4096, post_b2, nullptr,
        nullptr, nullptr, hbuf, nullptr, nullptr, nullptr, N);

    pool_kernel<<<G, 64, 0, stream>>>(hbuf, batch, pooled, N);
    post2_kernel<<<G, 128, 0, stream>>>(pooled, s4, solvent, p2w1, p2b1, p2w2, p2b2,
                                        p2w3, p2b3, out);
}

// Round 17
// 329.574 us; speedup vs baseline: 1.1231x; 1.1231x over previous
//
#include <hip/hip_runtime.h>
#include <hip/hip_bf16.h>
#include <hip/hip_fp16.h>

#define TABN   4096
#define ROWS   (TABN + 1)           // table rows per interaction
#define DMAX   6.5f
#define DELTA  (DMAX / (float)TABN)
#define INVD   ((float)TABN / DMAX)
#define LOG2F_ 0.6931471805599453f
#define SBITS  9                    // 512 tgt-nodes per bucket (R16 lesson: 8 regressed stage)
#define TILE   2048                 // edges per stage tile

typedef _Float16 f16x8 __attribute__((ext_vector_type(8)));
typedef float    f32x4 __attribute__((ext_vector_type(4)));

__device__ __forceinline__ float ssp(float x) {
    return fmaxf(x, 0.f) + __logf(1.f + __expf(-fabsf(x))) - LOG2F_;
}

// ---------------- filter lookup table: W_i(d) for d = t*DELTA ----------------
__global__ void ftab_kernel(const float* __restrict__ fw1, const float* __restrict__ fb1,
                            const float* __restrict__ fw2, const float* __restrict__ fb2,
                            float* __restrict__ ftab) {
    int t = blockIdx.x;          // 0..ROWS-1
    int i = blockIdx.y;          // interaction 0/1
    int j = threadIdx.x;         // 0..63 channel
    float d = (float)t * DELTA;
    float acc = fb1[i * 64 + j];
    for (int k = 0; k < 51; ++k) {
        float u = d - 0.1f * (float)k;
        float r = __expf(-10.f * u * u);
        acc = fmaf(r, fw1[((size_t)i * 51 + k) * 64 + j], acc);
    }
    __shared__ float h[64];
    h[j] = ssp(acc);
    __syncthreads();
    float o = fb2[i * 64 + j];
    for (int k = 0; k < 64; ++k)
        o = fmaf(h[k], fw2[((size_t)i * 64 + k) * 64 + j], o);
    ftab[((size_t)i * ROWS + t) * 64 + j] = o;
}

// ------- pack lerp endpoints as fp16 pair: 4B/entry, 1MB/interaction --------
__global__ void fpack_kernel(const float* __restrict__ ftab, __half2* __restrict__ fpair) {
    int t = blockIdx.x, i = blockIdx.y, j = threadIdx.x;
    const float* r = ftab + ((size_t)i * ROWS + t) * 64;
    fpair[((size_t)i * TABN + t) * 64 + j] = __floats2half2_rn(r[j], r[j + 64]);
}

// ------- pack/transpose the 7 64x64 node-MLP weights to [n][k] fp16 ---------
__global__ void wpack_kernel(const float* w0, const float* w1, const float* w2,
                             const float* w3, const float* w4, const float* w5,
                             const float* w6, __half* __restrict__ wt) {
    const float* ws[7] = {w0, w1, w2, w3, w4, w5, w6};
    int nrow = blockIdx.x, mat = blockIdx.y, k = threadIdx.x;
    wt[((size_t)mat * 64 + nrow) * 64 + k] = __float2half(ws[mat][k * 64 + nrow]);
}

// ---------------- bucket histogram (LDS-privatized) ----------------
__global__ void bhist_kernel(const int* __restrict__ ei, int* __restrict__ bcnt, int E) {
    __shared__ int h[256];
    int tid = threadIdx.x;
    h[tid] = 0;
    __syncthreads();
    for (int e = blockIdx.x * blockDim.x + tid; e < E; e += gridDim.x * blockDim.x)
        atomicAdd(&h[ei[E + e] >> SBITS], 1);
    __syncthreads();
    if (h[tid]) atomicAdd(&bcnt[tid], h[tid]);
}

// ---------------- bucket exclusive scan (parallel, one block) ----------------
__global__ void bscan_kernel(const int* __restrict__ bcnt, int* __restrict__ bbase,
                             int* __restrict__ bcur, int nbuck) {
    __shared__ int sm[256];
    int tid = threadIdx.x;
    int v = (tid < nbuck) ? bcnt[tid] : 0;
    sm[tid] = v;
    __syncthreads();
    for (int o = 1; o < 256; o <<= 1) {
        int t = (tid >= o) ? sm[tid - o] : 0;
        __syncthreads();
        sm[tid] += t;
        __syncthreads();
    }
    if (tid < nbuck) { bbase[tid] = sm[tid] - v; bcur[tid] = sm[tid] - v; }
    if (tid == 255) bbase[nbuck] = sm[255];
}

// ------- stage: LDS multisplit of edge tiles into bucket-ordered stg ---------
// payload: w0 = src | (t&511)<<17 ; w1 = ti<<20 | frac_q20
__global__ __launch_bounds__(256, 4)
void stage_kernel(const float* __restrict__ pos, const int* __restrict__ ei,
                  int* __restrict__ bcur, int2* __restrict__ stg, int E, int nbuck) {
    __shared__ int hist[256], loff[256], gbase[256], sc[256];
    __shared__ int2 sp[TILE];
    __shared__ short sb[TILE];
    int tid = threadIdx.x;
    int tile0 = blockIdx.x * TILE;
    int cnt = min(TILE, E - tile0);
    hist[tid] = 0;
    __syncthreads();
    int myrank[8], myb[8]; int2 mypay[8];
#pragma unroll
    for (int u = 0; u < 8; ++u) {
        int i = u * 256 + tid;
        myb[u] = -1;
        if (i < cnt) {
            int e = tile0 + i;
            int s = ei[e], t = ei[E + e];
            float dx = pos[3 * s]     - pos[3 * t];
            float dy = pos[3 * s + 1] - pos[3 * t + 1];
            float dz = pos[3 * s + 2] - pos[3 * t + 2];
            float d = sqrtf(dx * dx + dy * dy + dz * dz);
            float ds = fminf(d, DMAX) * INVD;
            int ti = min((int)ds, TABN - 1);
            int frq = min((int)((ds - (float)ti) * 1048576.f), 1048575);
            mypay[u] = make_int2(s | ((t & 511) << 17), (ti << 20) | frq);
            myb[u] = t >> SBITS;
            myrank[u] = atomicAdd(&hist[myb[u]], 1);
        }
    }
    __syncthreads();
    sc[tid] = hist[tid];
    __syncthreads();
    for (int o = 1; o < 256; o <<= 1) {
        int v = (tid >= o) ? sc[tid - o] : 0;
        __syncthreads();
        sc[tid] += v;
        __syncthreads();
    }
    loff[tid] = sc[tid] - hist[tid];
    if (tid < nbuck && hist[tid] > 0) gbase[tid] = atomicAdd(&bcur[tid], hist[tid]);
    __syncthreads();
#pragma unroll
    for (int u = 0; u < 8; ++u)
        if (myb[u] >= 0) {
            int idx = loff[myb[u]] + myrank[u];
            sp[idx] = mypay[u];
            sb[idx] = (short)myb[u];
        }
    __syncthreads();
    for (int i = tid; i < cnt; i += 256) {
        int b = sb[i];
        stg[gbase[b] + (i - loff[b])] = sp[i];
    }
}

// ------- place: per bucket, exact CSR placement with LDS-only atomics --------
__global__ __launch_bounds__(256)
void place_kernel(const int2* __restrict__ stg, const int* __restrict__ bbase,
                  int* __restrict__ off, int2* __restrict__ edata, int n, int nbuck) {
    int b = blockIdx.x;
    int n0 = b << SBITS;
    int nn = min(512, n - n0);
    int q0 = bbase[b], q1 = bbase[b + 1];
    __shared__ int cnt[512], cur[512], sc[256];
    int tid = threadIdx.x;
    cnt[tid] = 0; cnt[tid + 256] = 0;
    __syncthreads();
    for (int q = q0 + tid; q < q1; q += 256)
        atomicAdd(&cnt[(stg[q].x >> 17) & 511], 1);
    __syncthreads();
    int c0 = cnt[2 * tid], c1 = cnt[2 * tid + 1];
    int s = c0 + c1;
    sc[tid] = s;
    __syncthreads();
    for (int o = 1; o < 256; o <<= 1) {
        int v = (tid >= o) ? sc[tid - o] : 0;
        __syncthreads();
        sc[tid] += v;
        __syncthreads();
    }
    int run = sc[tid] - s;        // exclusive over node pairs
    cur[2 * tid] = run;
    cur[2 * tid + 1] = run + c0;
    if (2 * tid < nn)     off[n0 + 2 * tid]     = q0 + run;
    if (2 * tid + 1 < nn) off[n0 + 2 * tid + 1] = q0 + run + c0;
    if (b == nbuck - 1 && tid == 0) off[n] = q1;
    __syncthreads();
    for (int q = q0 + tid; q < q1; q += 256) {
        int2 v = stg[q];
        int p = atomicAdd(&cur[(v.x >> 17) & 511], 1);
        edata[q0 + p] = v;
    }
}

// ---------------- solvent head for the 4 unique solvent rows ----------------
__global__ void solv_kernel(const float* __restrict__ emb_solv,
                            const float* __restrict__ w1, const float* __restrict__ b1,
                            const float* __restrict__ w2, const float* __restrict__ b2,
                            float* __restrict__ s4) {
    __shared__ float h[4][64];
    int t = threadIdx.x, r = t >> 6, j = t & 63;
    float acc = b1[j];
    for (int k = 0; k < 64; ++k) acc = fmaf(emb_solv[r * 64 + k], w1[k * 64 + j], acc);
    h[r][j] = ssp(acc);
    __syncthreads();
    if (j < 32) {
        float a = b2[j];
        for (int k = 0; k < 64; ++k) a = fmaf(h[r][k], w2[k * 32 + j], a);
        s4[r * 32 + j] = a;
    }
}

// ------------- m0 = emb_z[z]@W+b, fp16 out; reads L1-resident emb table -----
__global__ __launch_bounds__(256, 4)
void mm1h_kernel(const int* __restrict__ z, const float* __restrict__ emb,
                 const float* __restrict__ w, const float* __restrict__ b,
                 __half* __restrict__ out, int n) {
    int tid = threadIdx.x;
    int q = __builtin_amdgcn_readfirstlane(tid >> 6);   // 0..3, wave-uniform
    int node = blockIdx.x * 64 + (tid & 63);
    node = min(node, n - 1);
    int zi = z[node];
    const float4* in4 = (const float4*)(emb + (size_t)zi * 64);  // 25KB table: L1 hit
    const float* wq = w + q * 16;
    const float* bq = b + q * 16;
    float acc[16];
#pragma unroll
    for (int j = 0; j < 16; ++j) acc[j] = bq[j];
#pragma unroll 2
    for (int kk = 0; kk < 16; ++kk) {
        float4 xv = in4[kk];
        const float* w0 = wq + kk * 256;
#pragma unroll
        for (int j = 0; j < 16; ++j) acc[j] = fmaf(xv.x, w0[j],       acc[j]);
#pragma unroll
        for (int j = 0; j < 16; ++j) acc[j] = fmaf(xv.y, w0[64 + j],  acc[j]);
#pragma unroll
        for (int j = 0; j < 16; ++j) acc[j] = fmaf(xv.z, w0[128 + j], acc[j]);
#pragma unroll
        for (int j = 0; j < 16; ++j) acc[j] = fmaf(xv.w, w0[192 + j], acc[j]);
    }
    __half2* o2 = (__half2*)(out + (size_t)node * 64 + q * 16);
#pragma unroll
    for (int c = 0; c < 8; ++c)
        o2[c] = __floats2half2_rn(acc[2 * c], acc[2 * c + 1]);
}

// ---------------- per-node aggregation: agg[t] = sum_e m[src]*W(d) ----------
// wave per tgt node; edata words readfirstlane'd -> SALU decode; m fp16 rows,
// fpair __half2 L2-resident; fp16 output (feeds only mfmlp layer 1).
__global__ void agg_kernel(const int* __restrict__ off, const int2* __restrict__ edata,
                           const __half* __restrict__ m, const __half2* __restrict__ fpair,
                           __half* __restrict__ agg, int n) {
    int wave = (blockIdx.x * blockDim.x + threadIdx.x) >> 6;
    int lane = threadIdx.x & 63;
    if (wave >= n) return;
    int e0 = __builtin_amdgcn_readfirstlane(off[wave]);
    int e1 = __builtin_amdgcn_readfirstlane(off[wave + 1]);
    const float FRS = 1.f / 1048576.f;
    float acc[4] = {0.f, 0.f, 0.f, 0.f};
    int e = e0;
    for (; e + 8 <= e1; e += 8) {
        float mv[8], wv[8];
#pragma unroll
        for (int u = 0; u < 8; ++u) {
            int2 pd = edata[e + u];
            int px = __builtin_amdgcn_readfirstlane(pd.x);
            int py = __builtin_amdgcn_readfirstlane(pd.y);
            int s = px & 0x1FFFF;
            unsigned ti = ((unsigned)py) >> 20;
            float fr = (float)(py & 0xFFFFF) * FRS;
            mv[u] = __half2float(m[(size_t)s * 64 + lane]);
            float2 wf = __half22float2(fpair[(size_t)ti * 64 + lane]);
            wv[u] = fmaf(fr, wf.y - wf.x, wf.x);
        }
#pragma unroll
        for (int u = 0; u < 8; ++u) acc[u & 3] = fmaf(mv[u], wv[u], acc[u & 3]);
    }
    for (; e + 4 <= e1; e += 4) {
        float mv[4], wv[4];
#pragma unroll
        for (int u = 0; u < 4; ++u) {
            int2 pd = edata[e + u];
            int px = __builtin_amdgcn_readfirstlane(pd.x);
            int py = __builtin_amdgcn_readfirstlane(pd.y);
            int s = px & 0x1FFFF;
            unsigned ti = ((unsigned)py) >> 20;
            float fr = (float)(py & 0xFFFFF) * FRS;
            mv[u] = __half2float(m[(size_t)s * 64 + lane]);
            float2 wf = __half22float2(fpair[(size_t)ti * 64 + lane]);
            wv[u] = fmaf(fr, wf.y - wf.x, wf.x);
        }
#pragma unroll
        for (int u = 0; u < 4; ++u) acc[u] = fmaf(mv[u], wv[u], acc[u]);
    }
    for (; e < e1; ++e) {
        int2 pd = edata[e];
        int px = __builtin_amdgcn_readfirstlane(pd.x);
        int py = __builtin_amdgcn_readfirstlane(pd.y);
        int s = px & 0x1FFFF;
        unsigned ti = ((unsigned)py) >> 20;
        float fr = (float)(py & 0xFFFFF) * FRS;
        float mm = __half2float(m[(size_t)s * 64 + lane]);
        float2 wf = __half22float2(fpair[(size_t)ti * 64 + lane]);
        acc[0] = fmaf(mm, fmaf(fr, wf.y - wf.x, wf.x), acc[0]);
    }
    agg[(size_t)wave * 64 + lane] = __float2half((acc[0] + acc[1]) + (acc[2] + acc[3]));
}

// ===== MFMA 2-layer node MLP: out = ssp(in@W1+b1)@W2+b2 (+res) (+next m) =====
// RESMODE: 0 = none, 1 = fp16 buffer, 2 = emb_z[z[r]] (L1-resident — kills the
// embed kernel). Layouts HW-verified (R14/R15).
template <int RESMODE, bool EMIT_M>
__global__ __launch_bounds__(256, 4)
void mfmlp_kernel(const __half* __restrict__ in,
                  const __half* __restrict__ w1t, const float* __restrict__ b1,
                  const __half* __restrict__ w2t, const float* __restrict__ b2,
                  const __half* __restrict__ res, const int* __restrict__ z,
                  const float* __restrict__ embf, __half* __restrict__ out,
                  const __half* __restrict__ lwt, const float* __restrict__ lb,
                  __half* __restrict__ mout, int n) {
    __shared__ __half hls[4][16][72];
    int tid = threadIdx.x;
    int w = tid >> 6, l = tid & 63;
    int lm = l & 15, lg = l >> 4;
    int base = blockIdx.x * 64 + w * 16;
    int arow = min(base + lm, n - 1);

    // ---- layer 1 ----
    f32x4 acc[4];
#pragma unroll
    for (int nt = 0; nt < 4; ++nt) acc[nt] = (f32x4){0.f, 0.f, 0.f, 0.f};
#pragma unroll
    for (int s = 0; s < 2; ++s) {
        f16x8 a = *(const f16x8*)(in + (size_t)arow * 64 + 32 * s + 8 * lg);
#pragma unroll
        for (int nt = 0; nt < 4; ++nt) {
            f16x8 b = *(const f16x8*)(w1t + (size_t)(lm + 16 * nt) * 64 + 32 * s + 8 * lg);
            acc[nt] = __builtin_amdgcn_mfma_f32_16x16x32_f16(a, b, acc[nt], 0, 0, 0);
        }
    }
#pragma unroll
    for (int nt = 0; nt < 4; ++nt) {
        float bb = b1[lm + 16 * nt];
#pragma unroll
        for (int i = 0; i < 4; ++i)
            hls[w][lg * 4 + i][lm + 16 * nt] = __float2half(ssp(acc[nt][i] + bb));
    }

    // ---- layer 2 ----
    f32x4 acc2[4];
#pragma unroll
    for (int nt = 0; nt < 4; ++nt) acc2[nt] = (f32x4){0.f, 0.f, 0.f, 0.f};
#pragma unroll
    for (int s = 0; s < 2; ++s) {
        f16x8 a = *(const f16x8*)(&hls[w][lm][32 * s + 8 * lg]);
#pragma unroll
        for (int nt = 0; nt < 4; ++nt) {
            f16x8 b = *(const f16x8*)(w2t + (size_t)(lm + 16 * nt) * 64 + 32 * s + 8 * lg);
            acc2[nt] = __builtin_amdgcn_mfma_f32_16x16x32_f16(a, b, acc2[nt], 0, 0, 0);
        }
    }
#pragma unroll
    for (int nt = 0; nt < 4; ++nt) {
        float bb = b2[lm + 16 * nt];
#pragma unroll
        for (int i = 0; i < 4; ++i) {
            int r = base + lg * 4 + i;
            if (r < n) {
                float v = acc2[nt][i] + bb;
                if constexpr (RESMODE == 1)
                    v += __half2float(res[(size_t)r * 64 + lm + 16 * nt]);
                else if constexpr (RESMODE == 2)
                    v += embf[(size_t)z[r] * 64 + lm + 16 * nt];
                out[(size_t)r * 64 + lm + 16 * nt] = __float2half(v);
                if constexpr (EMIT_M) hls[w][lg * 4 + i][lm + 16 * nt] = __float2half(v);
            }
        }
    }
    if constexpr (EMIT_M) {
        // ---- layer 3: next m = out-tile @ LW ----
        f32x4 acc3[4];
#pragma unroll
        for (int nt = 0; nt < 4; ++nt) acc3[nt] = (f32x4){0.f, 0.f, 0.f, 0.f};
#pragma unroll
        for (int s = 0; s < 2; ++s) {
            f16x8 a = *(const f16x8*)(&hls[w][lm][32 * s + 8 * lg]);
#pragma unroll
            for (int nt = 0; nt < 4; ++nt) {
                f16x8 b = *(const f16x8*)(lwt + (size_t)(lm + 16 * nt) * 64 + 32 * s + 8 * lg);
                acc3[nt] = __builtin_amdgcn_mfma_f32_16x16x32_f16(a, b, acc3[nt], 0, 0, 0);
            }
        }
#pragma unroll
        for (int nt = 0; nt < 4; ++nt) {
            float bb = lb[lm + 16 * nt];
#pragma unroll
            for (int i = 0; i < 4; ++i) {
                int r = base + lg * 4 + i;
                if (r < n)
                    mout[(size_t)r * 64 + lm + 16 * nt] = __float2half(acc3[nt][i] + bb);
            }
        }
    }
}

// ---------------- scatter-mean pooling (fp16 input, batch sorted) -----------
__global__ void pool_kernel(const __half* __restrict__ h, const int* __restrict__ batch,
                            float* __restrict__ pooled, int n_nodes) {
    int g = blockIdx.x, j = threadIdx.x;   // block = 64
    int lo = 0, hi = n_nodes;
    while (lo < hi) { int mid = (lo + hi) >> 1; if (batch[mid] < g) lo = mid + 1; else hi = mid; }
    int start = lo;
    int lo2 = start, hi2 = n_nodes;
    while (lo2 < hi2) { int mid = (lo2 + hi2) >> 1; if (batch[mid] < g + 1) lo2 = mid + 1; else hi2 = mid; }
    int end = lo2;
    float acc = 0.f;
    for (int r = start; r < end; ++r) acc += __half2float(h[(size_t)r * 64 + j]);
    float cnt = (float)(end - start);
    pooled[(size_t)g * 64 + j] = acc / fmaxf(cnt, 1.f);
}

// ---------------- final graph head: 96 -> 128 -> 32 -> 1 --------------------
__global__ void post2_kernel(const float* __restrict__ pooled, const float* __restrict__ s4,
                             const int* __restrict__ solvent,
                             const float* __restrict__ w1, const float* __restrict__ b1,
                             const float* __restrict__ w2, const float* __restrict__ b2,
                             const float* __restrict__ w3, const float* __restrict__ b3,
                             float* __restrict__ out) {
    __shared__ float in96[96];
    __shared__ float l1[128];
    __shared__ float l2[32];
    int g = blockIdx.x, t = threadIdx.x;   // block = 128
    if (t < 64)      in96[t] = pooled[(size_t)g * 64 + t];
    else if (t < 96) in96[t] = s4[solvent[g] * 32 + (t - 64)];
    __syncthreads();
    float acc = b1[t];
    for (int k = 0; k < 96; ++k) acc = fmaf(in96[k], w1[k * 128 + t], acc);
    l1[t] = ssp(acc);
    __syncthreads();
    if (t < 32) {
        float a = b2[t];
        for (int k = 0; k < 128; ++k) a = fmaf(l1[k], w2[k * 32 + t], a);
        l2[t] = ssp(a);
    }
    __syncthreads();
    if (t < 32) {
        float p = l2[t] * w3[t];
        for (int o = 16; o >= 1; o >>= 1) p += __shfl_down(p, o);
        if (t == 0) out[g] = p + b3[0];
    }
}

extern "C" void kernel_launch(void* const* d_in, const int* in_sizes, int n_in,
                              void* d_out, int out_size, void* d_ws, size_t ws_size,
                              hipStream_t stream) {
    const float* pos      = (const float*)d_in[0];
    const int*   ei       = (const int*)d_in[1];
    const int*   z        = (const int*)d_in[2];
    const int*   batch    = (const int*)d_in[3];
    const int*   solvent  = (const int*)d_in[4];
    const float* emb_z    = (const float*)d_in[5];
    const float* emb_solv = (const float*)d_in[6];
    const float* solv_w1  = (const float*)d_in[7];  const float* solv_b1 = (const float*)d_in[8];
    const float* solv_w2  = (const float*)d_in[9];  const float* solv_b2 = (const float*)d_in[10];
    const float* lin1_w   = (const float*)d_in[11]; const float* lin1_b  = (const float*)d_in[12];
    const float* mlp_w1   = (const float*)d_in[13]; const float* mlp_b1  = (const float*)d_in[14];
    const float* mlp_w2   = (const float*)d_in[15]; const float* mlp_b2  = (const float*)d_in[16];
    const float* filt_w1  = (const float*)d_in[17]; const float* filt_b1 = (const float*)d_in[18];
    const float* filt_w2  = (const float*)d_in[19]; const float* filt_b2 = (const float*)d_in[20];
    const float* post_w1  = (const float*)d_in[21]; const float* post_b1 = (const float*)d_in[22];
    const float* post_w2  = (const float*)d_in[23]; const float* post_b2 = (const float*)d_in[24];
    const float* p2w1 = (const float*)d_in[25]; const float* p2b1 = (const float*)d_in[26];
    const float* p2w2 = (const float*)d_in[27]; const float* p2b2 = (const float*)d_in[28];
    const float* p2w3 = (const float*)d_in[29]; const float* p2b3 = (const float*)d_in[30];
    float* out = (float*)d_out;

    const int N = in_sizes[2];
    const int E = in_sizes[1] / 2;
    const int G = in_sizes[4];
    const int NBUCK = (N + (1 << SBITS) - 1) >> SBITS;

    char* wp = (char*)d_ws;
    auto alloc = [&](size_t bytes) -> void* {
        void* r = (void*)wp;
        wp += (bytes + 255) & ~(size_t)255;
        return r;
    };
    int2*    stg    = (int2*)   alloc((size_t)E * 8);
    int2*    edata  = (int2*)   alloc((size_t)E * 8);
    int*     bcnt   = (int*)    alloc(256 * 4);
    int*     bbase  = (int*)    alloc(257 * 4);
    int*     bcur   = (int*)    alloc(256 * 4);
    int*     off    = (int*)    alloc((size_t)(N + 1) * 4);
    float*   ftab   = (float*)  alloc((size_t)2 * ROWS * 64 * 4);
    __half2* fpair  = (__half2*)alloc((size_t)2 * TABN * 64 * 4);
    __half*  wt     = (__half*) alloc((size_t)7 * 4096 * 2);
    float*   s4     = (float*)  alloc(4 * 32 * 4);
    __half*  x_h    = (__half*) alloc((size_t)N * 64 * 2);
    __half*  m_h    = (__half*) alloc((size_t)N * 64 * 2);
    __half*  m_h2   = (__half*) alloc((size_t)N * 64 * 2);
    __half*  agg_h  = (__half*) alloc((size_t)N * 64 * 2);
    __half*  hbuf   = (__half*) alloc((size_t)N * 64 * 2);
    float*   pooled = (float*)  alloc((size_t)G * 64 * 4);
    (void)ws_size; (void)n_in; (void)out_size;

    hipMemsetAsync(bcnt, 0, 256 * 4, stream);

    ftab_kernel<<<dim3(ROWS, 2), 64, 0, stream>>>(filt_w1, filt_b1, filt_w2, filt_b2, ftab);
    fpack_kernel<<<dim3(TABN, 2), 64, 0, stream>>>(ftab, fpair);
    // wt: 0=mlp_w1[0] 1=mlp_w2[0] 2=mlp_w1[1] 3=mlp_w2[1] 4=post_w1 5=post_w2 6=lin1_w[1]
    wpack_kernel<<<dim3(64, 7), 64, 0, stream>>>(mlp_w1, mlp_w2, mlp_w1 + 4096,
                                                 mlp_w2 + 4096, post_w1, post_w2,
                                                 lin1_w + 4096, wt);
    bhist_kernel<<<512, 256, 0, stream>>>(ei, bcnt, E);
    bscan_kernel<<<1, 256, 0, stream>>>(bcnt, bbase, bcur, NBUCK);
    stage_kernel<<<(E + TILE - 1) / TILE, 256, 0, stream>>>(pos, ei, bcur, stg, E, NBUCK);
    place_kernel<<<NBUCK, 256, 0, stream>>>(stg, bbase, off, edata, N, NBUCK);
    solv_kernel<<<1, 256, 0, stream>>>(emb_solv, solv_w1, solv_b1, solv_w2, solv_b2, s4);

    int mmg = (N + 63) / 64;
    // interaction 0: m0 = emb_z[z] @ lin1[0]
    mm1h_kernel<<<mmg, 256, 0, stream>>>(z, emb_z, lin1_w, lin1_b, m_h, N);
    agg_kernel<<<(N + 3) / 4, 256, 0, stream>>>(off, edata, m_h, fpair, agg_h, N);
    // MFMA MLP + residual(from L1-resident emb table) -> x_h, emit m1
    mfmlp_kernel<2, true><<<mmg, 256, 0, stream>>>(
        agg_h, wt, mlp_b1, wt + 4096, mlp_b2, nullptr, z, emb_z, x_h,
        wt + 6 * 4096, lin1_b + 64, m_h2, N);
    // interaction 1
    agg_kernel<<<(N + 3) / 4, 256, 0, stream>>>(off, edata, m_h2,
                                                fpair + (size_t)TABN * 64, agg_h, N);
    mfmlp_kernel<1, false><<<mmg, 256, 0, stream>>>(
        agg_h, wt + 2 * 4096, mlp_b1 + 64, wt + 3 * 4096, mlp_b2 + 64, x_h,
        nullptr, nullptr, x_h, nullptr, nullptr, nullptr, N);
    // post MLP: hbuf = ssp(x@pw1+b1)@pw2+b2 (fp16, feeds pool only)
    mfmlp_kernel<0, false><<<mmg, 256, 0, stream>>>(
        x_h, wt + 4 * 4096, post_b1, wt + 5 * 4096, post_b2, nullptr,
        nullptr, nullptr, hbuf, nullptr, nullptr, nullptr, N);

    pool_kernel<<<G, 64, 0, stream>>>(hbuf, batch, pooled, N);
    post2_kernel<<<G, 128, 0, stream>>>(pooled, s4, solvent, p2w1, p2b1, p2w2, p2b2,
                                        p2w3, p2b3, out);
}

// Round 18
// 310.619 us; speedup vs baseline: 1.1916x; 1.0610x over previous
//
#include <hip/hip_runtime.h>
#include <hip/hip_bf16.h>
#include <hip/hip_fp16.h>

#define TABN   4096
#define ROWS   (TABN + 1)           // table rows per interaction
#define DMAX   6.5f
#define DELTA  (DMAX / (float)TABN)
#define INVD   ((float)TABN / DMAX)
#define LOG2F_ 0.6931471805599453f
#define SBITS  9                    // 512 tgt-nodes per bucket
#define TILE   2048                 // edges per stage tile

typedef _Float16 f16x8 __attribute__((ext_vector_type(8)));
typedef float    f32x4 __attribute__((ext_vector_type(4)));

__device__ __forceinline__ float ssp(float x) {
    return fmaxf(x, 0.f) + __logf(1.f + __expf(-fabsf(x))) - LOG2F_;
}

// ------- filter table, fused fp16-pair emit: W_i(d)=row t -> fpair slots -----
// fpair[i][t] packs (W[t], W[t+1]) per channel as __half2; block (t,i) writes
// the x-half of row t and the y-half of row t-1 (2-byte stores, disjoint).
__global__ void ftabh_kernel(const float* __restrict__ fw1, const float* __restrict__ fb1,
                             const float* __restrict__ fw2, const float* __restrict__ fb2,
                             __half* __restrict__ fpairh) {
    int t = blockIdx.x;          // 0..TABN inclusive
    int i = blockIdx.y;          // interaction 0/1
    int j = threadIdx.x;         // 0..63 channel
    float d = (float)t * DELTA;
    float acc = fb1[i * 64 + j];
    for (int k = 0; k < 51; ++k) {
        float u = d - 0.1f * (float)k;
        float r = __expf(-10.f * u * u);
        acc = fmaf(r, fw1[((size_t)i * 51 + k) * 64 + j], acc);
    }
    __shared__ float h[64];
    h[j] = ssp(acc);
    __syncthreads();
    float o = fb2[i * 64 + j];
    for (int k = 0; k < 64; ++k)
        o = fmaf(h[k], fw2[((size_t)i * 64 + k) * 64 + j], o);
    __half hv = __float2half(o);
    if (t < TABN) fpairh[(((size_t)i * TABN + t) * 64 + j) * 2] = hv;
    if (t > 0)    fpairh[(((size_t)i * TABN + (t - 1)) * 64 + j) * 2 + 1] = hv;
}

// ------- pack/transpose the 7 64x64 node-MLP weights to [n][k] fp16 ---------
__global__ void wpack_kernel(const float* w0, const float* w1, const float* w2,
                             const float* w3, const float* w4, const float* w5,
                             const float* w6, __half* __restrict__ wt) {
    const float* ws[7] = {w0, w1, w2, w3, w4, w5, w6};
    int nrow = blockIdx.x, mat = blockIdx.y, k = threadIdx.x;
    wt[((size_t)mat * 64 + nrow) * 64 + k] = __float2half(ws[mat][k * 64 + nrow]);
}

// ---------------- bucket cursor init: bcur[b] = b*CAP ----------------
__global__ void binit_kernel(int* __restrict__ bcur, int nbuck, int cap) {
    int b = blockIdx.x * blockDim.x + threadIdx.x;
    if (b < nbuck) bcur[b] = b * cap;
}

// ------- stage: LDS multisplit of edge tiles into fixed-CAP bucket regions ---
// payload: w0 = src | (t&511)<<17 ; w1 = ti<<20 | frac_q20
__global__ __launch_bounds__(256, 4)
void stage_kernel(const float* __restrict__ pos, const int* __restrict__ ei,
                  int* __restrict__ bcur, int2* __restrict__ stg, int E, int nbuck,
                  int cap) {
    __shared__ int hist[256], loff[256], gbase[256], sc[256];
    __shared__ int2 sp[TILE];
    __shared__ short sb[TILE];
    int tid = threadIdx.x;
    int tile0 = blockIdx.x * TILE;
    int cnt = min(TILE, E - tile0);
    hist[tid] = 0;
    __syncthreads();
    int myrank[8], myb[8]; int2 mypay[8];
#pragma unroll
    for (int u = 0; u < 8; ++u) {
        int i = u * 256 + tid;
        myb[u] = -1;
        if (i < cnt) {
            int e = tile0 + i;
            int s = ei[e], t = ei[E + e];
            float dx = pos[3 * s]     - pos[3 * t];
            float dy = pos[3 * s + 1] - pos[3 * t + 1];
            float dz = pos[3 * s + 2] - pos[3 * t + 2];
            float d = sqrtf(dx * dx + dy * dy + dz * dz);
            float ds = fminf(d, DMAX) * INVD;
            int ti = min((int)ds, TABN - 1);
            int frq = min((int)((ds - (float)ti) * 1048576.f), 1048575);
            mypay[u] = make_int2(s | ((t & 511) << 17), (ti << 20) | frq);
            myb[u] = t >> SBITS;
            myrank[u] = atomicAdd(&hist[myb[u]], 1);
        }
    }
    __syncthreads();
    sc[tid] = hist[tid];
    __syncthreads();
    for (int o = 1; o < 256; o <<= 1) {
        int v = (tid >= o) ? sc[tid - o] : 0;
        __syncthreads();
        sc[tid] += v;
        __syncthreads();
    }
    loff[tid] = sc[tid] - hist[tid];
    if (tid < nbuck && hist[tid] > 0) gbase[tid] = atomicAdd(&bcur[tid], hist[tid]);
    __syncthreads();
#pragma unroll
    for (int u = 0; u < 8; ++u)
        if (myb[u] >= 0) {
            int idx = loff[myb[u]] + myrank[u];
            sp[idx] = mypay[u];
            sb[idx] = (short)myb[u];
        }
    __syncthreads();
    for (int i = tid; i < cnt; i += 256) {
        int b = sb[i];
        int idx = gbase[b] + (i - loff[b]);
        if (idx < (b + 1) * cap)            // overflow guard (never fires: 11-sigma slack)
            stg[idx] = sp[i];
    }
}

// ------- place: per bucket, exact CSR placement with LDS-only atomics --------
// buckets live in gapped [b*cap, bcur[b]) regions; emits per-node off/offE.
__global__ __launch_bounds__(256)
void place_kernel(const int2* __restrict__ stg, const int* __restrict__ bcur,
                  int* __restrict__ off, int* __restrict__ offE,
                  int2* __restrict__ edata, int n, int nbuck, int cap) {
    int b = blockIdx.x;
    int n0 = b << SBITS;
    int nn = min(512, n - n0);
    int q0 = b * cap;
    int q1 = min(bcur[b], q0 + cap);
    __shared__ int cnt[512], cur[512], sc[256];
    int tid = threadIdx.x;
    cnt[tid] = 0; cnt[tid + 256] = 0;
    __syncthreads();
    for (int q = q0 + tid; q < q1; q += 256)
        atomicAdd(&cnt[(stg[q].x >> 17) & 511], 1);
    __syncthreads();
    int c0 = cnt[2 * tid], c1 = cnt[2 * tid + 1];
    int s = c0 + c1;
    sc[tid] = s;
    __syncthreads();
    for (int o = 1; o < 256; o <<= 1) {
        int v = (tid >= o) ? sc[tid - o] : 0;
        __syncthreads();
        sc[tid] += v;
        __syncthreads();
    }
    int run = sc[tid] - s;        // exclusive over node pairs
    cur[2 * tid] = run;
    cur[2 * tid + 1] = run + c0;
    if (2 * tid < nn) {
        off[n0 + 2 * tid]  = q0 + run;
        offE[n0 + 2 * tid] = q0 + run + c0;
    }
    if (2 * tid + 1 < nn) {
        off[n0 + 2 * tid + 1]  = q0 + run + c0;
        offE[n0 + 2 * tid + 1] = q0 + run + c0 + c1;
    }
    __syncthreads();
    for (int q = q0 + tid; q < q1; q += 256) {
        int2 v = stg[q];
        int p = atomicAdd(&cur[(v.x >> 17) & 511], 1);
        edata[q0 + p] = v;
    }
}

// ---------------- solvent head for the 4 unique solvent rows ----------------
__global__ void solv_kernel(const float* __restrict__ emb_solv,
                            const float* __restrict__ w1, const float* __restrict__ b1,
                            const float* __restrict__ w2, const float* __restrict__ b2,
                            float* __restrict__ s4) {
    __shared__ float h[4][64];
    int t = threadIdx.x, r = t >> 6, j = t & 63;
    float acc = b1[j];
    for (int k = 0; k < 64; ++k) acc = fmaf(emb_solv[r * 64 + k], w1[k * 64 + j], acc);
    h[r][j] = ssp(acc);
    __syncthreads();
    if (j < 32) {
        float a = b2[j];
        for (int k = 0; k < 64; ++k) a = fmaf(h[r][k], w2[k * 32 + j], a);
        s4[r * 32 + j] = a;
    }
}

// ------------- m0 = emb_z[z]@W+b, fp16 out; reads L1-resident emb table -----
__global__ __launch_bounds__(256, 4)
void mm1h_kernel(const int* __restrict__ z, const float* __restrict__ emb,
                 const float* __restrict__ w, const float* __restrict__ b,
                 __half* __restrict__ out, int n) {
    int tid = threadIdx.x;
    int q = __builtin_amdgcn_readfirstlane(tid >> 6);   // 0..3, wave-uniform
    int node = blockIdx.x * 64 + (tid & 63);
    node = min(node, n - 1);
    int zi = z[node];
    const float4* in4 = (const float4*)(emb + (size_t)zi * 64);  // 25KB table: L1 hit
    const float* wq = w + q * 16;
    const float* bq = b + q * 16;
    float acc[16];
#pragma unroll
    for (int j = 0; j < 16; ++j) acc[j] = bq[j];
#pragma unroll 2
    for (int kk = 0; kk < 16; ++kk) {
        float4 xv = in4[kk];
        const float* w0 = wq + kk * 256;
#pragma unroll
        for (int j = 0; j < 16; ++j) acc[j] = fmaf(xv.x, w0[j],       acc[j]);
#pragma unroll
        for (int j = 0; j < 16; ++j) acc[j] = fmaf(xv.y, w0[64 + j],  acc[j]);
#pragma unroll
        for (int j = 0; j < 16; ++j) acc[j] = fmaf(xv.z, w0[128 + j], acc[j]);
#pragma unroll
        for (int j = 0; j < 16; ++j) acc[j] = fmaf(xv.w, w0[192 + j], acc[j]);
    }
    __half2* o2 = (__half2*)(out + (size_t)node * 64 + q * 16);
#pragma unroll
    for (int c = 0; c < 8; ++c)
        o2[c] = __floats2half2_rn(acc[2 * c], acc[2 * c + 1]);
}

// ---------------- per-node aggregation: agg[t] = sum_e m[src]*W(d) ----------
// wave per tgt node; edata words readfirstlane'd -> SALU decode; m fp16 rows,
// fpair __half2 L2-resident; fp16 output. e-range from off/offE (gapped CSR).
__global__ void agg_kernel(const int* __restrict__ off, const int* __restrict__ offE,
                           const int2* __restrict__ edata,
                           const __half* __restrict__ m, const __half2* __restrict__ fpair,
                           __half* __restrict__ agg, int n) {
    int wave = (blockIdx.x * blockDim.x + threadIdx.x) >> 6;
    int lane = threadIdx.x & 63;
    if (wave >= n) return;
    int e0 = __builtin_amdgcn_readfirstlane(off[wave]);
    int e1 = __builtin_amdgcn_readfirstlane(offE[wave]);
    const float FRS = 1.f / 1048576.f;
    float acc[4] = {0.f, 0.f, 0.f, 0.f};
    int e = e0;
    for (; e + 8 <= e1; e += 8) {
        float mv[8], wv[8];
#pragma unroll
        for (int u = 0; u < 8; ++u) {
            int2 pd = edata[e + u];
            int px = __builtin_amdgcn_readfirstlane(pd.x);
            int py = __builtin_amdgcn_readfirstlane(pd.y);
            int s = px & 0x1FFFF;
            unsigned ti = ((unsigned)py) >> 20;
            float fr = (float)(py & 0xFFFFF) * FRS;
            mv[u] = __half2float(m[(size_t)s * 64 + lane]);
            float2 wf = __half22float2(fpair[(size_t)ti * 64 + lane]);
            wv[u] = fmaf(fr, wf.y - wf.x, wf.x);
        }
#pragma unroll
        for (int u = 0; u < 8; ++u) acc[u & 3] = fmaf(mv[u], wv[u], acc[u & 3]);
    }
    for (; e + 4 <= e1; e += 4) {
        float mv[4], wv[4];
#pragma unroll
        for (int u = 0; u < 4; ++u) {
            int2 pd = edata[e + u];
            int px = __builtin_amdgcn_readfirstlane(pd.x);
            int py = __builtin_amdgcn_readfirstlane(pd.y);
            int s = px & 0x1FFFF;
            unsigned ti = ((unsigned)py) >> 20;
            float fr = (float)(py & 0xFFFFF) * FRS;
            mv[u] = __half2float(m[(size_t)s * 64 + lane]);
            float2 wf = __half22float2(fpair[(size_t)ti * 64 + lane]);
            wv[u] = fmaf(fr, wf.y - wf.x, wf.x);
        }
#pragma unroll
        for (int u = 0; u < 4; ++u) acc[u] = fmaf(mv[u], wv[u], acc[u]);
    }
    for (; e < e1; ++e) {
        int2 pd = edata[e];
        int px = __builtin_amdgcn_readfirstlane(pd.x);
        int py = __builtin_amdgcn_readfirstlane(pd.y);
        int s = px & 0x1FFFF;
        unsigned ti = ((unsigned)py) >> 20;
        float fr = (float)(py & 0xFFFFF) * FRS;
        float mm = __half2float(m[(size_t)s * 64 + lane]);
        float2 wf = __half22float2(fpair[(size_t)ti * 64 + lane]);
        acc[0] = fmaf(mm, fmaf(fr, wf.y - wf.x, wf.x), acc[0]);
    }
    agg[(size_t)wave * 64 + lane] = __float2half((acc[0] + acc[1]) + (acc[2] + acc[3]));
}

// ===== MFMA 2-layer node MLP: out = ssp(in@W1+b1)@W2+b2 (+res) (+next m) =====
// RESMODE: 0 = none, 1 = fp16 buffer, 2 = emb_z[z[r]] (L1-resident).
template <int RESMODE, bool EMIT_M>
__global__ __launch_bounds__(256, 4)
void mfmlp_kernel(const __half* __restrict__ in,
                  const __half* __restrict__ w1t, const float* __restrict__ b1,
                  const __half* __restrict__ w2t, const float* __restrict__ b2,
                  const __half* __restrict__ res, const int* __restrict__ z,
                  const float* __restrict__ embf, __half* __restrict__ out,
                  const __half* __restrict__ lwt, const float* __restrict__ lb,
                  __half* __restrict__ mout, int n) {
    __shared__ __half hls[4][16][72];
    int tid = threadIdx.x;
    int w = tid >> 6, l = tid & 63;
    int lm = l & 15, lg = l >> 4;
    int base = blockIdx.x * 64 + w * 16;
    int arow = min(base + lm, n - 1);

    // ---- layer 1 ----
    f32x4 acc[4];
#pragma unroll
    for (int nt = 0; nt < 4; ++nt) acc[nt] = (f32x4){0.f, 0.f, 0.f, 0.f};
#pragma unroll
    for (int s = 0; s < 2; ++s) {
        f16x8 a = *(const f16x8*)(in + (size_t)arow * 64 + 32 * s + 8 * lg);
#pragma unroll
        for (int nt = 0; nt < 4; ++nt) {
            f16x8 b = *(const f16x8*)(w1t + (size_t)(lm + 16 * nt) * 64 + 32 * s + 8 * lg);
            acc[nt] = __builtin_amdgcn_mfma_f32_16x16x32_f16(a, b, acc[nt], 0, 0, 0);
        }
    }
#pragma unroll
    for (int nt = 0; nt < 4; ++nt) {
        float bb = b1[lm + 16 * nt];
#pragma unroll
        for (int i = 0; i < 4; ++i)
            hls[w][lg * 4 + i][lm + 16 * nt] = __float2half(ssp(acc[nt][i] + bb));
    }

    // ---- layer 2 ----
    f32x4 acc2[4];
#pragma unroll
    for (int nt = 0; nt < 4; ++nt) acc2[nt] = (f32x4){0.f, 0.f, 0.f, 0.f};
#pragma unroll
    for (int s = 0; s < 2; ++s) {
        f16x8 a = *(const f16x8*)(&hls[w][lm][32 * s + 8 * lg]);
#pragma unroll
        for (int nt = 0; nt < 4; ++nt) {
            f16x8 b = *(const f16x8*)(w2t + (size_t)(lm + 16 * nt) * 64 + 32 * s + 8 * lg);
            acc2[nt] = __builtin_amdgcn_mfma_f32_16x16x32_f16(a, b, acc2[nt], 0, 0, 0);
        }
    }
#pragma unroll
    for (int nt = 0; nt < 4; ++nt) {
        float bb = b2[lm + 16 * nt];
#pragma unroll
        for (int i = 0; i < 4; ++i) {
            int r = base + lg * 4 + i;
            if (r < n) {
                float v = acc2[nt][i] + bb;
                if constexpr (RESMODE == 1)
                    v += __half2float(res[(size_t)r * 64 + lm + 16 * nt]);
                else if constexpr (RESMODE == 2)
                    v += embf[(size_t)z[r] * 64 + lm + 16 * nt];
                out[(size_t)r * 64 + lm + 16 * nt] = __float2half(v);
                if constexpr (EMIT_M) hls[w][lg * 4 + i][lm + 16 * nt] = __float2half(v);
            }
        }
    }
    if constexpr (EMIT_M) {
        // ---- layer 3: next m = out-tile @ LW ----
        f32x4 acc3[4];
#pragma unroll
        for (int nt = 0; nt < 4; ++nt) acc3[nt] = (f32x4){0.f, 0.f, 0.f, 0.f};
#pragma unroll
        for (int s = 0; s < 2; ++s) {
            f16x8 a = *(const f16x8*)(&hls[w][lm][32 * s + 8 * lg]);
#pragma unroll
            for (int nt = 0; nt < 4; ++nt) {
                f16x8 b = *(const f16x8*)(lwt + (size_t)(lm + 16 * nt) * 64 + 32 * s + 8 * lg);
                acc3[nt] = __builtin_amdgcn_mfma_f32_16x16x32_f16(a, b, acc3[nt], 0, 0, 0);
            }
        }
#pragma unroll
        for (int nt = 0; nt < 4; ++nt) {
            float bb = lb[lm + 16 * nt];
#pragma unroll
            for (int i = 0; i < 4; ++i) {
                int r = base + lg * 4 + i;
                if (r < n)
                    mout[(size_t)r * 64 + lm + 16 * nt] = __float2half(acc3[nt][i] + bb);
            }
        }
    }
}

// ---------------- scatter-mean pooling (fp16 input, batch sorted) -----------
__global__ void pool_kernel(const __half* __restrict__ h, const int* __restrict__ batch,
                            float* __restrict__ pooled, int n_nodes) {
    int g = blockIdx.x, j = threadIdx.x;   // block = 64
    int lo = 0, hi = n_nodes;
    while (lo < hi) { int mid = (lo + hi) >> 1; if (batch[mid] < g) lo = mid + 1; else hi = mid; }
    int start = lo;
    int lo2 = start, hi2 = n_nodes;
    while (lo2 < hi2) { int mid = (lo2 + hi2) >> 1; if (batch[mid] < g + 1) lo2 = mid + 1; else hi2 = mid; }
    int end = lo2;
    float acc = 0.f;
    for (int r = start; r < end; ++r) acc += __half2float(h[(size_t)r * 64 + j]);
    float cnt = (float)(end - start);
    pooled[(size_t)g * 64 + j] = acc / fmaxf(cnt, 1.f);
}

// ---------------- final graph head: 96 -> 128 -> 32 -> 1 --------------------
__global__ void post2_kernel(const float* __restrict__ pooled, const float* __restrict__ s4,
                             const int* __restrict__ solvent,
                             const float* __restrict__ w1, const float* __restrict__ b1,
                             const float* __restrict__ w2, const float* __restrict__ b2,
                             const float* __restrict__ w3, const float* __restrict__ b3,
                             float* __restrict__ out) {
    __shared__ float in96[96];
    __shared__ float l1[128];
    __shared__ float l2[32];
    int g = blockIdx.x, t = threadIdx.x;   // block = 128
    if (t < 64)      in96[t] = pooled[(size_t)g * 64 + t];
    else if (t < 96) in96[t] = s4[solvent[g] * 32 + (t - 64)];
    __syncthreads();
    float acc = b1[t];
    for (int k = 0; k < 96; ++k) acc = fmaf(in96[k], w1[k * 128 + t], acc);
    l1[t] = ssp(acc);
    __syncthreads();
    if (t < 32) {
        float a = b2[t];
        for (int k = 0; k < 128; ++k) a = fmaf(l1[k], w2[k * 32 + t], a);
        l2[t] = ssp(a);
    }
    __syncthreads();
    if (t < 32) {
        float p = l2[t] * w3[t];
        for (int o = 16; o >= 1; o >>= 1) p += __shfl_down(p, o);
        if (t == 0) out[g] = p + b3[0];
    }
}

extern "C" void kernel_launch(void* const* d_in, const int* in_sizes, int n_in,
                              void* d_out, int out_size, void* d_ws, size_t ws_size,
                              hipStream_t stream) {
    const float* pos      = (const float*)d_in[0];
    const int*   ei       = (const int*)d_in[1];
    const int*   z        = (const int*)d_in[2];
    const int*   batch    = (const int*)d_in[3];
    const int*   solvent  = (const int*)d_in[4];
    const float* emb_z    = (const float*)d_in[5];
    const float* emb_solv = (const float*)d_in[6];
    const float* solv_w1  = (const float*)d_in[7];  const float* solv_b1 = (const float*)d_in[8];
    const float* solv_w2  = (const float*)d_in[9];  const float* solv_b2 = (const float*)d_in[10];
    const float* lin1_w   = (const float*)d_in[11]; const float* lin1_b  = (const float*)d_in[12];
    const float* mlp_w1   = (const float*)d_in[13]; const float* mlp_b1  = (const float*)d_in[14];
    const float* mlp_w2   = (const float*)d_in[15]; const float* mlp_b2  = (const float*)d_in[16];
    const float* filt_w1  = (const float*)d_in[17]; const float* filt_b1 = (const float*)d_in[18];
    const float* filt_w2  = (const float*)d_in[19]; const float* filt_b2 = (const float*)d_in[20];
    const float* post_w1  = (const float*)d_in[21]; const float* post_b1 = (const float*)d_in[22];
    const float* post_w2  = (const float*)d_in[23]; const float* post_b2 = (const float*)d_in[24];
    const float* p2w1 = (const float*)d_in[25]; const float* p2b1 = (const float*)d_in[26];
    const float* p2w2 = (const float*)d_in[27]; const float* p2b2 = (const float*)d_in[28];
    const float* p2w3 = (const float*)d_in[29]; const float* p2b3 = (const float*)d_in[30];
    float* out = (float*)d_out;

    const int N = in_sizes[2];
    const int E = in_sizes[1] / 2;
    const int G = in_sizes[4];
    const int NBUCK = (N + (1 << SBITS) - 1) >> SBITS;
    const int CAP = E / NBUCK + 1024;   // mean + ~11 sigma slack

    char* wp = (char*)d_ws;
    auto alloc = [&](size_t bytes) -> void* {
        void* r = (void*)wp;
        wp += (bytes + 255) & ~(size_t)255;
        return r;
    };
    int2*    stg    = (int2*)   alloc((size_t)NBUCK * CAP * 8);
    int2*    edata  = (int2*)   alloc((size_t)NBUCK * CAP * 8);
    int*     bcur   = (int*)    alloc(256 * 4);
    int*     off    = (int*)    alloc((size_t)N * 4);
    int*     offE   = (int*)    alloc((size_t)N * 4);
    __half2* fpair  = (__half2*)alloc((size_t)2 * TABN * 64 * 4);
    __half*  wt     = (__half*) alloc((size_t)7 * 4096 * 2);
    float*   s4     = (float*)  alloc(4 * 32 * 4);
    __half*  x_h    = (__half*) alloc((size_t)N * 64 * 2);
    __half*  m_h    = (__half*) alloc((size_t)N * 64 * 2);
    __half*  m_h2   = (__half*) alloc((size_t)N * 64 * 2);
    __half*  agg_h  = (__half*) alloc((size_t)N * 64 * 2);
    __half*  hbuf   = (__half*) alloc((size_t)N * 64 * 2);
    float*   pooled = (float*)  alloc((size_t)G * 64 * 4);
    (void)ws_size; (void)n_in; (void)out_size;

    binit_kernel<<<1, 256, 0, stream>>>(bcur, NBUCK, CAP);
    ftabh_kernel<<<dim3(ROWS, 2), 64, 0, stream>>>(filt_w1, filt_b1, filt_w2, filt_b2,
                                                   (__half*)fpair);
    // wt: 0=mlp_w1[0] 1=mlp_w2[0] 2=mlp_w1[1] 3=mlp_w2[1] 4=post_w1 5=post_w2 6=lin1_w[1]
    wpack_kernel<<<dim3(64, 7), 64, 0, stream>>>(mlp_w1, mlp_w2, mlp_w1 + 4096,
                                                 mlp_w2 + 4096, post_w1, post_w2,
                                                 lin1_w + 4096, wt);
    stage_kernel<<<(E + TILE - 1) / TILE, 256, 0, stream>>>(pos, ei, bcur, stg, E,
                                                            NBUCK, CAP);
    place_kernel<<<NBUCK, 256, 0, stream>>>(stg, bcur, off, offE, edata, N, NBUCK, CAP);
    solv_kernel<<<1, 256, 0, stream>>>(emb_solv, solv_w1, solv_b1, solv_w2, solv_b2, s4);

    int mmg = (N + 63) / 64;
    // interaction 0: m0 = emb_z[z] @ lin1[0]
    mm1h_kernel<<<mmg, 256, 0, stream>>>(z, emb_z, lin1_w, lin1_b, m_h, N);
    agg_kernel<<<(N + 3) / 4, 256, 0, stream>>>(off, offE, edata, m_h, fpair, agg_h, N);
    // MFMA MLP + residual(from L1-resident emb table) -> x_h, emit m1
    mfmlp_kernel<2, true><<<mmg, 256, 0, stream>>>(
        agg_h, wt, mlp_b1, wt + 4096, mlp_b2, nullptr, z, emb_z, x_h,
        wt + 6 * 4096, lin1_b + 64, m_h2, N);
    // interaction 1
    agg_kernel<<<(N + 3) / 4, 256, 0, stream>>>(off, offE, edata, m_h2,
                                                fpair + (size_t)TABN * 64, agg_h, N);
    mfmlp_kernel<1, false><<<mmg, 256, 0, stream>>>(
        agg_h, wt + 2 * 4096, mlp_b1 + 64, wt + 3 * 4096, mlp_b2 + 64, x_h,
        nullptr, nullptr, x_h, nullptr, nullptr, nullptr, N);
    // post MLP: hbuf = ssp(x@pw1+b1)@pw2+b2 (fp16, feeds pool only)
    mfmlp_kernel<0, false><<<mmg, 256, 0, stream>>>(
        x_h, wt + 4 * 4096, post_b1, wt + 5 * 4096, post_b2, nullptr,
        nullptr, nullptr, hbuf, nullptr, nullptr, nullptr, N);

    pool_kernel<<<G, 64, 0, stream>>>(hbuf, batch, pooled, N);
    post2_kernel<<<G, 128, 0, stream>>>(pooled, s4, solvent, p2w1, p2b1, p2w2, p2b2,
                                        p2w3, p2b3, out);
}